// Round 16
// baseline (81.443 us; speedup 1.0000x reference)
//
#include <hip/hip_runtime.h>
#include <math.h>

#define DD 128
#define HH 256
#define WD 256
#define HWS (HH*WD)
#define VOLS ((size_t)DD*HWS)
#define DC 16          // slices per wave-tile -> 8 d-chunks (champion R11)
#define NT 512         // 8 waves/block
#define NWG 256        // 2048 waves: 4 vols x 8 dt x 64 ht
#define FINF (__builtin_inff())

__device__ __forceinline__ float min3f(float a, float b, float c) {
  return fminf(fminf(a, b), c);   // fuses to v_min3_f32
}
__device__ __forceinline__ float max3f(float a, float b, float c) {
  return fmaxf(fmaxf(a, b), c);   // fuses to v_max3_f32
}

#define MIN3V(d,a,b,c) do{ (d).x=min3f((a).x,(b).x,(c).x); (d).y=min3f((a).y,(b).y,(c).y); \
                           (d).z=min3f((a).z,(b).z,(c).z); (d).w=min3f((a).w,(b).w,(c).w);}while(0)
#define MAX3V(d,a,b,c) do{ (d).x=max3f((a).x,(b).x,(c).x); (d).y=max3f((a).y,(b).y,(c).y); \
                           (d).z=max3f((a).z,(b).z,(c).z); (d).w=max3f((a).w,(b).w,(c).w);}while(0)
#define SET4(d,val)    do{ (d).x=(val); (d).y=(val); (d).z=(val); (d).w=(val);}while(0)

// Guarded stage-load of slice (ZNARG) into VRN[8] (+inf outside volume /
// beyond the last compute slice; h-border rows +inf via hOK*).
#define PLOAD(ZNARG, VRN) do {                                                \
    const int zn = (ZNARG);                                                   \
    if (zn >= 0 && zn < DD && zn <= d0 + DC + 1) {                            \
      const float* znb = imgL + (size_t)zn * HWS;                             \
      if (hOK0) VRN[0] = *(const float4*)(znb - 2*WD); else SET4(VRN[0],FINF);\
      if (hOK1) VRN[1] = *(const float4*)(znb - 1*WD); else SET4(VRN[1],FINF);\
      VRN[2] = *(const float4*)(znb);                                         \
      VRN[3] = *(const float4*)(znb + 1*WD);                                  \
      VRN[4] = *(const float4*)(znb + 2*WD);                                  \
      VRN[5] = *(const float4*)(znb + 3*WD);                                  \
      if (hOK6) VRN[6] = *(const float4*)(znb + 4*WD); else SET4(VRN[6],FINF);\
      if (hOK7) VRN[7] = *(const float4*)(znb + 5*WD); else SET4(VRN[7],FINF);\
    } else {                                                                  \
      _Pragma("unroll") for (int zr = 0; zr < 8; ++zr) SET4(VRN[zr], FINF);   \
    }                                                                         \
  } while (0)

// One step, half-step software pipeline (R16): compute slice zS from VRC
// (staged by the PREVIOUS step's prefetch); after H-min/D-min retire VRC,
// issue the prefetch of slice zS+1 into VRN -> its L2 latency hides under
// the W-min/dilation/skel tail (~60% of the step). ic/ot keep full-step
// slack. All macro locals z-prefixed (R4 lesson).
#define STEPP(SARG, VRC, VRN, M2WR, MXWR) do {                                \
    const int  zS    = (SARG);                                                \
    const bool zeOK  = (zS >= 1 && zS <= DD);   /* er slice e=zS-1 in-volume */\
    const int  zo    = zS - 2;                                                \
    const bool zoOut = (zS >= d0 + 2);                                        \
    float4 ic[4], ot[4];                                                      \
    if (zoOut) {                                                              \
      const float* zib = imgL + (size_t)zo * HWS;                             \
      const float* zob = othL + (size_t)zo * HWS;                             \
      _Pragma("unroll") for (int zr = 0; zr < 4; ++zr) {                      \
        ic[zr] = *(const float4*)(zib + zr*WD);                               \
        ot[zr] = *(const float4*)(zob + zr*WD);                               \
      }                                                                       \
    }                                                                         \
    /* H-min (consumes VRC) and D-min -> er; VRC dead after this */           \
    float4 hm[6], er[6];                                                      \
    _Pragma("unroll") for (int ri = 0; ri < 6; ++ri)                          \
      MIN3V(hm[ri], VRC[ri], VRC[ri+1], VRC[ri+2]);                           \
    _Pragma("unroll") for (int ri = 0; ri < 6; ++ri) {                        \
      MIN3V(er[ri], hm[ri], m2_0[ri], m2_1[ri]);                              \
      M2WR[ri] = hm[ri];                                                      \
    }                                                                         \
    /* prefetch next slice into VRN (pressure-neutral: VRC just died) */      \
    PLOAD(zS + 1, VRN);                                                       \
    /* W-min (2 shuffles x 6 rows), dilation mask, D-max */                   \
    float4 qd[6];                                                             \
    _Pragma("unroll") for (int ri = 0; ri < 6; ++ri) {                        \
      float zlw = __shfl_up(er[ri].w, 1);   zlw = (lane == 0)  ? FINF : zlw;  \
      float zrx = __shfl_down(er[ri].x, 1); zrx = (lane == 63) ? FINF : zrx;  \
      float4 zew;                                                             \
      zew.x = min3f(zlw, er[ri].x, er[ri].y);                                 \
      zew.y = min3f(er[ri].x, er[ri].y, er[ri].z);                            \
      zew.z = min3f(er[ri].y, er[ri].z, er[ri].w);                            \
      zew.w = min3f(er[ri].z, er[ri].w, zrx);                                 \
      if (!(zeOK && ehOK[ri])) SET4(zew, -FINF);  /* outside-volume er */     \
      MAX3V(qd[ri], zew, mx_0[ri], mx_1[ri]);                                 \
      MXWR[ri] = zew;                                                         \
    }                                                                         \
    /* H-max, W-max (2 shuffles x 4 rows), skel, fused reduce */              \
    if (zoOut) {                                                              \
      _Pragma("unroll") for (int zr = 0; zr < 4; ++zr) {                      \
        float4 zon; MAX3V(zon, qd[zr], qd[zr+1], qd[zr+2]);                   \
        float zel = __shfl_up(zon.w, 1);   zel = (lane == 0)  ? -FINF : zel;  \
        float zer = __shfl_down(zon.x, 1); zer = (lane == 63) ? -FINF : zer;  \
        float4 zop;                                                           \
        zop.x = max3f(zel, zon.x, zon.y);                                     \
        zop.y = max3f(zon.x, zon.y, zon.z);                                   \
        zop.z = max3f(zon.y, zon.z, zon.w);                                   \
        zop.w = max3f(zon.z, zon.w, zer);                                     \
        float4 zsk;                                                           \
        zsk.x = fmaxf(ic[zr].x - zop.x, 0.f);                                 \
        zsk.y = fmaxf(ic[zr].y - zop.y, 0.f);                                 \
        zsk.z = fmaxf(ic[zr].z - zop.z, 0.f);                                 \
        zsk.w = fmaxf(ic[zr].w - zop.w, 0.f);                                 \
        accN4.x += zsk.x * ot[zr].x; accN4.y += zsk.y * ot[zr].y;             \
        accN4.z += zsk.z * ot[zr].z; accN4.w += zsk.w * ot[zr].w;             \
        accD4.x += zsk.x; accD4.y += zsk.y;                                   \
        accD4.z += zsk.z; accD4.w += zsk.w;                                   \
      }                                                                       \
    }                                                                         \
  } while (0)

// No waves-per-eu hint (R6: clamps+spills; R8: no residency gain).
// No XCD swizzle (R10->R11: broke L3 locality at DC=16, +74MB FETCH).
// Full 20-step unroll, absolute addressing (R13: runtime-loop form spilled).
__global__ __launch_bounds__(NT) void skel_reduce_kernel(
    const float* __restrict__ y_pred, const float* __restrict__ y_true,
    double* __restrict__ acc)
{
  __shared__ float red[2][8];

  const int tid  = threadIdx.x;
  const int wid  = tid >> 6;                 // 0..7
  const int lane = tid & 63;
  const int gwv  = blockIdx.x * 8 + wid;     // 0..2047
  const int ht = gwv & 63;                   // 64 h-tiles of 4 rows
  const int dt = (gwv >> 6) & 7;             // 8 d-chunks of 16 slices
  const int v  = gwv >> 9;                   // role*2 + b (block-uniform)
  const int role = v >> 1, b = v & 1;

  const float* img = (role == 0 ? y_pred : y_true) + (size_t)b * VOLS;
  const float* oth = (role == 0 ? y_true : y_pred) + (size_t)b * VOLS;

  const int h0 = ht * 4, d0 = dt * DC;
  const float* imgL = img + (size_t)h0 * WD + 4 * lane;
  const float* othL = oth + (size_t)h0 * WD + 4 * lane;

  // h-border validity (wave-uniform); staged rows h0-2 .. h0+5
  const bool hOK0 = (h0 - 2 >= 0), hOK1 = (h0 - 1 >= 0);
  const bool hOK6 = (h0 + 4 < HH), hOK7 = (h0 + 5 < HH);
  bool ehOK[6];
  #pragma unroll
  for (int i = 0; i < 6; ++i) ehOK[i] = ((unsigned)(h0 + i - 1) < HH);

  // Ping-pong D-state per slice parity: m2_* = H-min, mx_* = masked erosion.
  float4 m2_0[6], m2_1[6], mx_0[6], mx_1[6];
  #pragma unroll
  for (int i = 0; i < 6; ++i) {
    SET4(m2_0[i], FINF);  SET4(m2_1[i], FINF);
    SET4(mx_0[i], -FINF); SET4(mx_1[i], -FINF);
  }
  float4 accN4, accD4; SET4(accN4, 0.f); SET4(accD4, 0.f);

  // vr double-buffer: vra = even compute slices, vrb = odd (compile-time
  // parity in the 2x-unrolled loop).
  float4 vra[8], vrb[8];

  // Prologue: stage the first compute slice (d0-2) into vra.
  PLOAD(d0 - 2, vra);

  // d0 even -> slice parity is compile-time in the 2x-unrolled loop.
  for (int SS = d0 - 2; SS < d0 + DC + 2; SS += 2) {
    STEPP(SS,     vra, vrb, m2_0, mx_1);
    STEPP(SS + 1, vrb, vra, m2_1, mx_0);
  }

  float accN = accN4.x + accN4.y + accN4.z + accN4.w;
  float accD = accD4.x + accD4.y + accD4.z + accD4.w;
  #pragma unroll
  for (int off = 32; off > 0; off >>= 1) {
    accN += __shfl_down(accN, off);
    accD += __shfl_down(accD, off);
  }
  if (lane == 0) { red[0][wid] = accN; red[1][wid] = accD; }
  __syncthreads();
  if (tid == 0) {
    float n = 0.f, dn = 0.f;
    #pragma unroll
    for (int w = 0; w < 8; ++w) { n += red[0][w]; dn += red[1][w]; }
    atomicAdd(&acc[v * 2 + 0], (double)n);
    atomicAdd(&acc[v * 2 + 1], (double)dn);
  }
}

__global__ void finalize_kernel(const double* __restrict__ acc,
                                float* __restrict__ out)
{
  const double smooth = 1e-5;
  double cl[2];
  for (int b = 0; b < 2; ++b) {
    double tprec = acc[(0 * 2 + b) * 2 + 0] / (acc[(0 * 2 + b) * 2 + 1] + smooth);
    double tsens = acc[(1 * 2 + b) * 2 + 0] / (acc[(1 * 2 + b) * 2 + 1] + smooth);
    cl[b] = 2.0 * tprec * tsens / (tprec + tsens + smooth);
  }
  out[0] = (float)(1.0 - 0.5 * (cl[0] + cl[1]));
}

extern "C" void kernel_launch(void* const* d_in, const int* in_sizes, int n_in,
                              void* d_out, int out_size, void* d_ws, size_t ws_size,
                              hipStream_t stream) {
  const float* y_pred = (const float*)d_in[0];
  const float* y_true = (const float*)d_in[1];
  double* acc = (double*)d_ws;
  hipMemsetAsync(d_ws, 0, 8 * sizeof(double), stream);
  // 2048 waves: 4 role-vols x 8 d-chunks x 64 h-tiles -> 256 blocks x 8 waves
  skel_reduce_kernel<<<dim3(NWG), dim3(NT), 0, stream>>>(y_pred, y_true, acc);
  finalize_kernel<<<dim3(1), dim3(1), 0, stream>>>(acc, (float*)d_out);
}

// Round 17
// 62.491 us; speedup vs baseline: 1.3033x; 1.3033x over previous
//
#include <hip/hip_runtime.h>
#include <math.h>

#define DD 128
#define HH 256
#define WD 256
#define HWS (HH*WD)
#define VOLS ((size_t)DD*HWS)
#define DC 16          // slices per wave-tile -> 8 d-chunks (champion R11)
#define NT 512         // 8 waves/block
#define NWG 256        // 2048 waves: 4 vols x 8 dt x 64 ht
#define FINF (__builtin_inff())

__device__ __forceinline__ float min3f(float a, float b, float c) {
  return fminf(fminf(a, b), c);   // fuses to v_min3_f32
}
__device__ __forceinline__ float max3f(float a, float b, float c) {
  return fmaxf(fmaxf(a, b), c);   // fuses to v_max3_f32
}

// async global->LDS, 16B/lane: global src per-lane, LDS dest WAVE-UNIFORM
// base (HW adds lane*16). Zero VGPRs for in-flight data (R17 mechanism).
__device__ __forceinline__ void gload16(const float* g, float* l) {
  __builtin_amdgcn_global_load_lds(
      (const __attribute__((address_space(1))) void*)g,
      (__attribute__((address_space(3))) void*)l, 16, 0, 0);
}

#define MIN3V(d,a,b,c) do{ (d).x=min3f((a).x,(b).x,(c).x); (d).y=min3f((a).y,(b).y,(c).y); \
                           (d).z=min3f((a).z,(b).z,(c).z); (d).w=min3f((a).w,(b).w,(c).w);}while(0)
#define MAX3V(d,a,b,c) do{ (d).x=max3f((a).x,(b).x,(c).x); (d).y=max3f((a).y,(b).y,(c).y); \
                           (d).z=max3f((a).z,(b).z,(c).z); (d).w=max3f((a).w,(b).w,(c).w);}while(0)
#define SET4(d,val)    do{ (d).x=(val); (d).y=(val); (d).z=(val); (d).w=(val);}while(0)

// Issue the 8 async stage rows of slice (ZNARG) into LDS buf PB.
// Slice index and h-border rows use CLAMPED addresses (always-safe, always
// 8 loads -> uniform vmcnt arithmetic); values corrected at read time.
#define GSTAGE(ZNARG, PB) do {                                                \
    int zn = (ZNARG); zn = zn < 0 ? 0 : (zn > DD - 1 ? DD - 1 : zn);          \
    const float* znb = imgL + (size_t)zn * HWS;                               \
    gload16(znb + zoff0, &LBUF[wid][PB][0][0]);                               \
    gload16(znb + zoff1, &LBUF[wid][PB][1][0]);                               \
    gload16(znb,         &LBUF[wid][PB][2][0]);                               \
    gload16(znb + 1*WD,  &LBUF[wid][PB][3][0]);                               \
    gload16(znb + 2*WD,  &LBUF[wid][PB][4][0]);                               \
    gload16(znb + 3*WD,  &LBUF[wid][PB][5][0]);                               \
    gload16(znb + zoff6, &LBUF[wid][PB][6][0]);                               \
    gload16(znb + zoff7, &LBUF[wid][PB][7][0]);                               \
  } while (0)

// One step (R17): [1] async-stage slice zS+1 into buf PBN (zero-reg in
// flight); [2] counted s_waitcnt vmcnt(8) = drain ONLY the previous step's
// batch (this step's 8 stay in flight across the whole step — T4 idiom);
// [3] ds_read buf PBC -> vr (short-lived regs); compute = R11 exactly.
// sched_barrier(0) fences per rule 18 (compiler doesn't order ds_read vs
// inline-asm vmcnt). All macro locals z-prefixed (R4 lesson).
#define STEPL(SARG, PBC, PBN, M2WR, MXWR) do {                                \
    const int  zS    = (SARG);                                                \
    const bool zsOK  = (zS >= 0 && zS < DD);                                  \
    const bool zeOK  = (zS >= 1 && zS <= DD);   /* er slice e=zS-1 in-volume */\
    const int  zo    = zS - 2;                                                \
    const bool zoOut = (zS >= d0 + 2);                                        \
    GSTAGE(zS + 1, PBN);                                                      \
    __builtin_amdgcn_sched_barrier(0);                                        \
    asm volatile("s_waitcnt vmcnt(8)" ::: "memory");                          \
    __builtin_amdgcn_sched_barrier(0);                                        \
    float4 vr[8];                                                             \
    _Pragma("unroll") for (int zr = 0; zr < 8; ++zr)                          \
      vr[zr] = *reinterpret_cast<const float4*>(&LBUF[wid][PBC][zr][lane*4]); \
    if (zsOK) {                                                               \
      if (!hOK0) SET4(vr[0], FINF);                                           \
      if (!hOK1) SET4(vr[1], FINF);                                           \
      if (!hOK6) SET4(vr[6], FINF);                                           \
      if (!hOK7) SET4(vr[7], FINF);                                           \
    } else {                                                                  \
      _Pragma("unroll") for (int zr = 0; zr < 8; ++zr) SET4(vr[zr], FINF);    \
    }                                                                         \
    float4 ic[4], ot[4];                                                      \
    if (zoOut) {                                                              \
      const float* zib = imgL + (size_t)zo * HWS;                             \
      const float* zob = othL + (size_t)zo * HWS;                             \
      _Pragma("unroll") for (int zr = 0; zr < 4; ++zr) {                      \
        ic[zr] = *(const float4*)(zib + zr*WD);                               \
        ot[zr] = *(const float4*)(zob + zr*WD);                               \
      }                                                                       \
    }                                                                         \
    /* H-min (pure VALU, 6 independent chains) */                             \
    float4 hm[6], er[6];                                                      \
    _Pragma("unroll") for (int ri = 0; ri < 6; ++ri)                          \
      MIN3V(hm[ri], vr[ri], vr[ri+1], vr[ri+2]);                              \
    /* D-min via ping-pong; read old state then overwrite */                  \
    _Pragma("unroll") for (int ri = 0; ri < 6; ++ri) {                        \
      MIN3V(er[ri], hm[ri], m2_0[ri], m2_1[ri]);                              \
      M2WR[ri] = hm[ri];                                                      \
    }                                                                         \
    /* W-min (2 shuffles x 6 rows), dilation mask, D-max */                   \
    float4 qd[6];                                                             \
    _Pragma("unroll") for (int ri = 0; ri < 6; ++ri) {                        \
      float zlw = __shfl_up(er[ri].w, 1);   zlw = (lane == 0)  ? FINF : zlw;  \
      float zrx = __shfl_down(er[ri].x, 1); zrx = (lane == 63) ? FINF : zrx;  \
      float4 zew;                                                             \
      zew.x = min3f(zlw, er[ri].x, er[ri].y);                                 \
      zew.y = min3f(er[ri].x, er[ri].y, er[ri].z);                            \
      zew.z = min3f(er[ri].y, er[ri].z, er[ri].w);                            \
      zew.w = min3f(er[ri].z, er[ri].w, zrx);                                 \
      if (!(zeOK && ehOK[ri])) SET4(zew, -FINF);  /* outside-volume er */     \
      MAX3V(qd[ri], zew, mx_0[ri], mx_1[ri]);                                 \
      MXWR[ri] = zew;                                                         \
    }                                                                         \
    /* H-max, W-max (2 shuffles x 4 rows), skel, fused reduce */              \
    if (zoOut) {                                                              \
      _Pragma("unroll") for (int zr = 0; zr < 4; ++zr) {                      \
        float4 zon; MAX3V(zon, qd[zr], qd[zr+1], qd[zr+2]);                   \
        float zel = __shfl_up(zon.w, 1);   zel = (lane == 0)  ? -FINF : zel;  \
        float zer = __shfl_down(zon.x, 1); zer = (lane == 63) ? -FINF : zer;  \
        float4 zop;                                                           \
        zop.x = max3f(zel, zon.x, zon.y);                                     \
        zop.y = max3f(zon.x, zon.y, zon.z);                                   \
        zop.z = max3f(zon.y, zon.z, zon.w);                                   \
        zop.w = max3f(zon.z, zon.w, zer);                                     \
        float4 zsk;                                                           \
        zsk.x = fmaxf(ic[zr].x - zop.x, 0.f);                                 \
        zsk.y = fmaxf(ic[zr].y - zop.y, 0.f);                                 \
        zsk.z = fmaxf(ic[zr].z - zop.z, 0.f);                                 \
        zsk.w = fmaxf(ic[zr].w - zop.w, 0.f);                                 \
        accN4.x += zsk.x * ot[zr].x; accN4.y += zsk.y * ot[zr].y;             \
        accN4.z += zsk.z * ot[zr].z; accN4.w += zsk.w * ot[zr].w;             \
        accD4.x += zsk.x; accD4.y += zsk.y;                                   \
        accD4.z += zsk.z; accD4.w += zsk.w;                                   \
      }                                                                       \
    }                                                                         \
  } while (0)

// No waves-per-eu hint (R6: clamps+spills; R8: no residency gain).
// No XCD swizzle (R10->R11: broke L3 locality at DC=16, +74MB FETCH).
// Full 20-step unroll, absolute addressing (R13: runtime-loop form spilled).
// LDS 128KB/block -> 1 block/CU, which is residency already (NWG=256=#CUs).
__global__ __launch_bounds__(NT) void skel_reduce_kernel(
    const float* __restrict__ y_pred, const float* __restrict__ y_true,
    double* __restrict__ acc)
{
  __shared__ float LBUF[8][2][8][256];   // [wave][buf][row][lane*4] = 128 KiB
  __shared__ float red[2][8];

  const int tid  = threadIdx.x;
  const int wid  = tid >> 6;                 // 0..7
  const int lane = tid & 63;
  const int gwv  = blockIdx.x * 8 + wid;     // 0..2047
  const int ht = gwv & 63;                   // 64 h-tiles of 4 rows
  const int dt = (gwv >> 6) & 7;             // 8 d-chunks of 16 slices
  const int v  = gwv >> 9;                   // role*2 + b (block-uniform)
  const int role = v >> 1, b = v & 1;

  const float* img = (role == 0 ? y_pred : y_true) + (size_t)b * VOLS;
  const float* oth = (role == 0 ? y_true : y_pred) + (size_t)b * VOLS;

  const int h0 = ht * 4, d0 = dt * DC;
  const float* imgL = img + (size_t)h0 * WD + 4 * lane;
  const float* othL = oth + (size_t)h0 * WD + 4 * lane;

  // h-border validity (wave-uniform); staged rows h0-2 .. h0+5
  const bool hOK0 = (h0 - 2 >= 0), hOK1 = (h0 - 1 >= 0);
  const bool hOK6 = (h0 + 4 < HH), hOK7 = (h0 + 5 < HH);
  bool ehOK[6];
  #pragma unroll
  for (int i = 0; i < 6; ++i) ehOK[i] = ((unsigned)(h0 + i - 1) < HH);
  // clamped stage offsets (always-valid addresses; value fixed at read)
  const int zoff0 = hOK0 ? -2*WD : 0;
  const int zoff1 = hOK1 ? -1*WD : 0;
  const int zoff6 = hOK6 ?  4*WD : 0;
  const int zoff7 = hOK7 ?  5*WD : 0;

  // Ping-pong D-state per slice parity: m2_* = H-min, mx_* = masked erosion.
  float4 m2_0[6], m2_1[6], mx_0[6], mx_1[6];
  #pragma unroll
  for (int i = 0; i < 6; ++i) {
    SET4(m2_0[i], FINF);  SET4(m2_1[i], FINF);
    SET4(mx_0[i], -FINF); SET4(mx_1[i], -FINF);
  }
  float4 accN4, accD4; SET4(accN4, 0.f); SET4(accD4, 0.f);

  // Prologue: async-stage the first compute slice (d0-2) into buf 0.
  GSTAGE(d0 - 2, 0);

  // d0 even -> slice parity/buffer index compile-time in the 2x-unrolled loop.
  for (int SS = d0 - 2; SS < d0 + DC + 2; SS += 2) {
    STEPL(SS,     0, 1, m2_0, mx_1);
    STEPL(SS + 1, 1, 0, m2_1, mx_0);
  }

  float accN = accN4.x + accN4.y + accN4.z + accN4.w;
  float accD = accD4.x + accD4.y + accD4.z + accD4.w;
  #pragma unroll
  for (int off = 32; off > 0; off >>= 1) {
    accN += __shfl_down(accN, off);
    accD += __shfl_down(accD, off);
  }
  if (lane == 0) { red[0][wid] = accN; red[1][wid] = accD; }
  __syncthreads();
  if (tid == 0) {
    float n = 0.f, dn = 0.f;
    #pragma unroll
    for (int w = 0; w < 8; ++w) { n += red[0][w]; dn += red[1][w]; }
    atomicAdd(&acc[v * 2 + 0], (double)n);
    atomicAdd(&acc[v * 2 + 1], (double)dn);
  }
}

__global__ void finalize_kernel(const double* __restrict__ acc,
                                float* __restrict__ out)
{
  const double smooth = 1e-5;
  double cl[2];
  for (int b = 0; b < 2; ++b) {
    double tprec = acc[(0 * 2 + b) * 2 + 0] / (acc[(0 * 2 + b) * 2 + 1] + smooth);
    double tsens = acc[(1 * 2 + b) * 2 + 0] / (acc[(1 * 2 + b) * 2 + 1] + smooth);
    cl[b] = 2.0 * tprec * tsens / (tprec + tsens + smooth);
  }
  out[0] = (float)(1.0 - 0.5 * (cl[0] + cl[1]));
}

extern "C" void kernel_launch(void* const* d_in, const int* in_sizes, int n_in,
                              void* d_out, int out_size, void* d_ws, size_t ws_size,
                              hipStream_t stream) {
  const float* y_pred = (const float*)d_in[0];
  const float* y_true = (const float*)d_in[1];
  double* acc = (double*)d_ws;
  hipMemsetAsync(d_ws, 0, 8 * sizeof(double), stream);
  // 2048 waves: 4 role-vols x 8 d-chunks x 64 h-tiles -> 256 blocks x 8 waves
  skel_reduce_kernel<<<dim3(NWG), dim3(NT), 0, stream>>>(y_pred, y_true, acc);
  finalize_kernel<<<dim3(1), dim3(1), 0, stream>>>(acc, (float*)d_out);
}

// Round 18
// 52.518 us; speedup vs baseline: 1.5508x; 1.1899x over previous
//
#include <hip/hip_runtime.h>
#include <math.h>

#define DD 128
#define HH 256
#define WD 256
#define HWS (HH*WD)
#define VOLS ((size_t)DD*HWS)
#define DC 16          // slices per wave-tile -> 8 d-chunks (champion)
#define NT 512         // 8 waves/block (R11: big blocks raise residency)
#define NWG 256        // 2048 waves: 4 vols x 8 dt x 64 ht
#define FINF (__builtin_inff())

// ============================================================================
// CHAMPION (R11, 52.6us). Structural constraints mapped over R12-R17:
//  - HBM compulsory ~131MB = ~21us of the ~53us wall.
//  - Time ~ 1:1 with per-step instruction count at >=8 waves/CU (R12/R14).
//  - Any in-flight-state scheme crosses the VGPR=128 cliff (R9/R13/R16) or
//    adds instructions (R17 zero-reg async staging: +ds_reads, +fences).
//  - TLP beyond ~8 waves/CU adds nothing (R12); shuffle pipe not binding
//    (R15 DPP swap flat); XCD swizzle breaks L3 locality at DC=16 (R10).
// ============================================================================

__device__ __forceinline__ float min3f(float a, float b, float c) {
  return fminf(fminf(a, b), c);   // fuses to v_min3_f32
}
__device__ __forceinline__ float max3f(float a, float b, float c) {
  return fmaxf(fmaxf(a, b), c);   // fuses to v_max3_f32
}

#define MIN3V(d,a,b,c) do{ (d).x=min3f((a).x,(b).x,(c).x); (d).y=min3f((a).y,(b).y,(c).y); \
                           (d).z=min3f((a).z,(b).z,(c).z); (d).w=min3f((a).w,(b).w,(c).w);}while(0)
#define MAX3V(d,a,b,c) do{ (d).x=max3f((a).x,(b).x,(c).x); (d).y=max3f((a).y,(b).y,(c).y); \
                           (d).z=max3f((a).z,(b).z,(c).z); (d).w=max3f((a).w,(b).w,(c).w);}while(0)
#define SET4(d,val)    do{ (d).x=(val); (d).y=(val); (d).z=(val); (d).w=(val);}while(0)

// One step, 4 output rows/wave, W-outermost ordering (20 shuffles/step).
// Separable passes commute within erosion and within dilation:
// erode = minW(minD(minH)), dilate = maxW(maxH(maxD)).
// m2_0/m2_1 ping-pong: H-min of the 2 previous slices (by parity);
// mx_0/mx_1: masked W-min-complete erosion of the 2 previous slices.
// All macro locals z-prefixed (R4 lesson: no self-init shadowing).
#define STEPW(SARG, M2WR, MXWR) do {                                          \
    const int  zS    = (SARG);                                                \
    const bool zsOK  = (zS >= 0 && zS < DD);                                  \
    const bool zeOK  = (zS >= 1 && zS <= DD);   /* er slice e=zS-1 in-volume */\
    const int  zo    = zS - 2;                                                \
    const bool zoOut = (zS >= d0 + 2);                                        \
    float4 vr[8];                                                             \
    if (zsOK) {                                                               \
      const float* zsb = imgL + (size_t)zS * HWS;                             \
      if (hOK0) vr[0] = *(const float4*)(zsb - 2*WD); else SET4(vr[0], FINF); \
      if (hOK1) vr[1] = *(const float4*)(zsb - 1*WD); else SET4(vr[1], FINF); \
      vr[2] = *(const float4*)(zsb);                                          \
      vr[3] = *(const float4*)(zsb + 1*WD);                                   \
      vr[4] = *(const float4*)(zsb + 2*WD);                                   \
      vr[5] = *(const float4*)(zsb + 3*WD);                                   \
      if (hOK6) vr[6] = *(const float4*)(zsb + 4*WD); else SET4(vr[6], FINF); \
      if (hOK7) vr[7] = *(const float4*)(zsb + 5*WD); else SET4(vr[7], FINF); \
    } else {                                                                  \
      _Pragma("unroll") for (int zr = 0; zr < 8; ++zr) SET4(vr[zr], FINF);    \
    }                                                                         \
    float4 ic[4], ot[4];                                                      \
    if (zoOut) {                                                              \
      const float* zib = imgL + (size_t)zo * HWS;                             \
      const float* zob = othL + (size_t)zo * HWS;                             \
      _Pragma("unroll") for (int zr = 0; zr < 4; ++zr) {                      \
        ic[zr] = *(const float4*)(zib + zr*WD);                               \
        ot[zr] = *(const float4*)(zob + zr*WD);                               \
      }                                                                       \
    }                                                                         \
    /* H-min (pure VALU, 6 independent chains) */                             \
    float4 hm[6], er[6];                                                      \
    _Pragma("unroll") for (int ri = 0; ri < 6; ++ri)                          \
      MIN3V(hm[ri], vr[ri], vr[ri+1], vr[ri+2]);                              \
    /* D-min via ping-pong; read old state then overwrite */                  \
    _Pragma("unroll") for (int ri = 0; ri < 6; ++ri) {                        \
      MIN3V(er[ri], hm[ri], m2_0[ri], m2_1[ri]);                              \
      M2WR[ri] = hm[ri];                                                      \
    }                                                                         \
    /* W-min (2 shuffles x 6 rows), dilation mask, D-max */                   \
    float4 qd[6];                                                             \
    _Pragma("unroll") for (int ri = 0; ri < 6; ++ri) {                        \
      float zlw = __shfl_up(er[ri].w, 1);   zlw = (lane == 0)  ? FINF : zlw;  \
      float zrx = __shfl_down(er[ri].x, 1); zrx = (lane == 63) ? FINF : zrx;  \
      float4 zew;                                                             \
      zew.x = min3f(zlw, er[ri].x, er[ri].y);                                 \
      zew.y = min3f(er[ri].x, er[ri].y, er[ri].z);                            \
      zew.z = min3f(er[ri].y, er[ri].z, er[ri].w);                            \
      zew.w = min3f(er[ri].z, er[ri].w, zrx);                                 \
      if (!(zeOK && ehOK[ri])) SET4(zew, -FINF);  /* outside-volume er */     \
      MAX3V(qd[ri], zew, mx_0[ri], mx_1[ri]);                                 \
      MXWR[ri] = zew;                                                         \
    }                                                                         \
    /* H-max, W-max (2 shuffles x 4 rows), skel, fused reduce */              \
    if (zoOut) {                                                              \
      _Pragma("unroll") for (int zr = 0; zr < 4; ++zr) {                      \
        float4 zon; MAX3V(zon, qd[zr], qd[zr+1], qd[zr+2]);                   \
        float zel = __shfl_up(zon.w, 1);   zel = (lane == 0)  ? -FINF : zel;  \
        float zer = __shfl_down(zon.x, 1); zer = (lane == 63) ? -FINF : zer;  \
        float4 zop;                                                           \
        zop.x = max3f(zel, zon.x, zon.y);                                     \
        zop.y = max3f(zon.x, zon.y, zon.z);                                   \
        zop.z = max3f(zon.y, zon.z, zon.w);                                   \
        zop.w = max3f(zon.z, zon.w, zer);                                     \
        float4 zsk;                                                           \
        zsk.x = fmaxf(ic[zr].x - zop.x, 0.f);                                 \
        zsk.y = fmaxf(ic[zr].y - zop.y, 0.f);                                 \
        zsk.z = fmaxf(ic[zr].z - zop.z, 0.f);                                 \
        zsk.w = fmaxf(ic[zr].w - zop.w, 0.f);                                 \
        accN4.x += zsk.x * ot[zr].x; accN4.y += zsk.y * ot[zr].y;             \
        accN4.z += zsk.z * ot[zr].z; accN4.w += zsk.w * ot[zr].w;             \
        accD4.x += zsk.x; accD4.y += zsk.y;                                   \
        accD4.z += zsk.z; accD4.w += zsk.w;                                   \
      }                                                                       \
    }                                                                         \
  } while (0)

// No waves-per-eu hint (R6: clamps VGPR + spills; R8: no residency gain).
// No XCD swizzle (R10->R11: broke L3 locality at DC=16, +74MB FETCH).
// Full 20-step unroll, absolute addressing (R13: runtime-loop form spilled).
__global__ __launch_bounds__(NT) void skel_reduce_kernel(
    const float* __restrict__ y_pred, const float* __restrict__ y_true,
    double* __restrict__ acc)
{
  __shared__ float red[2][8];

  const int tid  = threadIdx.x;
  const int wid  = tid >> 6;                 // 0..7
  const int lane = tid & 63;
  const int gwv  = blockIdx.x * 8 + wid;     // 0..2047
  const int ht = gwv & 63;                   // 64 h-tiles of 4 rows
  const int dt = (gwv >> 6) & 7;             // 8 d-chunks of 16 slices
  const int v  = gwv >> 9;                   // role*2 + b (block-uniform)
  const int role = v >> 1, b = v & 1;

  const float* img = (role == 0 ? y_pred : y_true) + (size_t)b * VOLS;
  const float* oth = (role == 0 ? y_true : y_pred) + (size_t)b * VOLS;

  const int h0 = ht * 4, d0 = dt * DC;
  const float* imgL = img + (size_t)h0 * WD + 4 * lane;
  const float* othL = oth + (size_t)h0 * WD + 4 * lane;

  // h-border validity (wave-uniform); staged rows h0-2 .. h0+5
  const bool hOK0 = (h0 - 2 >= 0), hOK1 = (h0 - 1 >= 0);
  const bool hOK6 = (h0 + 4 < HH), hOK7 = (h0 + 5 < HH);
  bool ehOK[6];
  #pragma unroll
  for (int i = 0; i < 6; ++i) ehOK[i] = ((unsigned)(h0 + i - 1) < HH);

  // Ping-pong D-state per slice parity: m2_* = H-min, mx_* = masked erosion.
  float4 m2_0[6], m2_1[6], mx_0[6], mx_1[6];
  #pragma unroll
  for (int i = 0; i < 6; ++i) {
    SET4(m2_0[i], FINF);  SET4(m2_1[i], FINF);
    SET4(mx_0[i], -FINF); SET4(mx_1[i], -FINF);
  }
  float4 accN4, accD4; SET4(accN4, 0.f); SET4(accD4, 0.f);

  // d0 even -> slice parity is compile-time in the 2x-unrolled loop.
  for (int SS = d0 - 2; SS < d0 + DC + 2; SS += 2) {
    STEPW(SS,     m2_0, mx_1);
    STEPW(SS + 1, m2_1, mx_0);
  }

  float accN = accN4.x + accN4.y + accN4.z + accN4.w;
  float accD = accD4.x + accD4.y + accD4.z + accD4.w;
  #pragma unroll
  for (int off = 32; off > 0; off >>= 1) {
    accN += __shfl_down(accN, off);
    accD += __shfl_down(accD, off);
  }
  if (lane == 0) { red[0][wid] = accN; red[1][wid] = accD; }
  __syncthreads();
  if (tid == 0) {
    float n = 0.f, dn = 0.f;
    #pragma unroll
    for (int w = 0; w < 8; ++w) { n += red[0][w]; dn += red[1][w]; }
    atomicAdd(&acc[v * 2 + 0], (double)n);
    atomicAdd(&acc[v * 2 + 1], (double)dn);
  }
}

__global__ void finalize_kernel(const double* __restrict__ acc,
                                float* __restrict__ out)
{
  const double smooth = 1e-5;
  double cl[2];
  for (int b = 0; b < 2; ++b) {
    double tprec = acc[(0 * 2 + b) * 2 + 0] / (acc[(0 * 2 + b) * 2 + 1] + smooth);
    double tsens = acc[(1 * 2 + b) * 2 + 0] / (acc[(1 * 2 + b) * 2 + 1] + smooth);
    cl[b] = 2.0 * tprec * tsens / (tprec + tsens + smooth);
  }
  out[0] = (float)(1.0 - 0.5 * (cl[0] + cl[1]));
}

extern "C" void kernel_launch(void* const* d_in, const int* in_sizes, int n_in,
                              void* d_out, int out_size, void* d_ws, size_t ws_size,
                              hipStream_t stream) {
  const float* y_pred = (const float*)d_in[0];
  const float* y_true = (const float*)d_in[1];
  double* acc = (double*)d_ws;
  hipMemsetAsync(d_ws, 0, 8 * sizeof(double), stream);
  // 2048 waves: 4 role-vols x 8 d-chunks x 64 h-tiles -> 256 blocks x 8 waves
  skel_reduce_kernel<<<dim3(NWG), dim3(NT), 0, stream>>>(y_pred, y_true, acc);
  finalize_kernel<<<dim3(1), dim3(1), 0, stream>>>(acc, (float*)d_out);
}